// Round 1
// baseline (621.316 us; speedup 1.0000x reference)
//
#include <hip/hip_runtime.h>
#include <hip/hip_bf16.h>

// Problem: out[M,N] = data[M,K] @ (mask*weight)[N,K]^T + bias[N]
// M=8192, N=4096, K=4096, fp32 in/out.
// Strategy: convert data and (mask*weight) to bf16 in d_ws, then m97-style
// 128x128-tile bf16 MFMA GEMM (16x16x32), global_load_lds width-16 staging.

#define Mdim 8192
#define Ndim 4096
#define Kdim 4096

typedef __bf16 bf16x8 __attribute__((ext_vector_type(8)));
typedef float f32x4 __attribute__((ext_vector_type(4)));

// round-to-nearest-even fp32 -> bf16 bits
__device__ inline unsigned short f2bf(float f) {
    union { float f; unsigned u; } v;
    v.f = f;
    unsigned r = v.u + 0x7fffu + ((v.u >> 16) & 1u);
    return (unsigned short)(r >> 16);
}

// async global->LDS, 16B per lane; lds_ptr per-lane = base + lane*16
#define GLOAD_LDS16(gp, lp)                                                     \
    __builtin_amdgcn_global_load_lds((const __attribute__((address_space(1))) void*)(gp), \
                                     (__attribute__((address_space(3))) void*)(lp), 16, 0, 0)

// ---- conversion kernels (memory-bound, float4 loads) ----
__global__ void k_cvt_data(const float4* __restrict__ x, ushort4* __restrict__ y, int n4) {
    int i = blockIdx.x * blockDim.x + threadIdx.x;
    if (i < n4) {
        float4 v = x[i];
        ushort4 o;
        o.x = f2bf(v.x); o.y = f2bf(v.y); o.z = f2bf(v.z); o.w = f2bf(v.w);
        y[i] = o;
    }
}

__global__ void k_cvt_w(const float4* __restrict__ w, const float4* __restrict__ m,
                        ushort4* __restrict__ y, int n4) {
    int i = blockIdx.x * blockDim.x + threadIdx.x;
    if (i < n4) {
        float4 wv = w[i];
        float4 mv = m[i];
        ushort4 o;
        o.x = f2bf(wv.x * mv.x); o.y = f2bf(wv.y * mv.y);
        o.z = f2bf(wv.z * mv.z); o.w = f2bf(wv.w * mv.w);
        y[i] = o;
    }
}

// ---- bf16 MFMA GEMM: C = A * B^T + bias ----
// A [M,K] bf16 row-major, B [N,K] bf16 row-major (i.e. B^T input), C [M,N] f32.
// Block = 256 threads = 4 waves; tile 128x128, BK=32; each wave does 64x64
// via 4x4 grid of 16x16x32 MFMAs.
__global__ __launch_bounds__(256) void k_gemm(const unsigned short* __restrict__ A,
                                              const unsigned short* __restrict__ B,
                                              const float* __restrict__ bias,
                                              float* __restrict__ out) {
    __shared__ unsigned short As[128 * 32];  // 8 KB, row-major [128][32]
    __shared__ unsigned short Bs[128 * 32];  // 8 KB

    const int tid  = threadIdx.x;
    const int lane = tid & 63;
    const int wave = tid >> 6;
    const int wm   = (wave >> 1) * 64;  // wave row offset within tile
    const int wn   = (wave & 1) * 64;   // wave col offset within tile
    const int bm   = blockIdx.y * 128;
    const int bn   = blockIdx.x * 128;

    // staging: per wave two 16-row chunks of A-tile and B-tile.
    // lane l covers tile-row c*16 + (l>>2), 8 elements at col (l&3)*8.
    const int ar = lane >> 2;
    const int ac = (lane & 3) * 8;
    const unsigned short* Ag0 = A + (size_t)(bm + wave * 32 + ar) * Kdim + ac;
    const unsigned short* Ag1 = Ag0 + (size_t)16 * Kdim;
    const unsigned short* Bg0 = B + (size_t)(bn + wave * 32 + ar) * Kdim + ac;
    const unsigned short* Bg1 = Bg0 + (size_t)16 * Kdim;
    // LDS destinations: chunk c -> element offset c*512 + lane*8 (== base + lane*16B)
    unsigned short* Al0 = As + wave * 1024 + lane * 8;
    unsigned short* Al1 = Al0 + 512;
    unsigned short* Bl0 = Bs + wave * 1024 + lane * 8;
    unsigned short* Bl1 = Bl0 + 512;

    f32x4 zero = {0.f, 0.f, 0.f, 0.f};
    f32x4 acc[4][4];
#pragma unroll
    for (int i = 0; i < 4; ++i)
#pragma unroll
        for (int j = 0; j < 4; ++j) acc[i][j] = zero;

    const int fr = lane & 15;        // row within 16x16 fragment
    const int fk = (lane >> 4) * 8;  // k offset within fragment

    for (int k0 = 0; k0 < Kdim; k0 += 32) {
        GLOAD_LDS16(Ag0 + k0, Al0);
        GLOAD_LDS16(Ag1 + k0, Al1);
        GLOAD_LDS16(Bg0 + k0, Bl0);
        GLOAD_LDS16(Bg1 + k0, Bl1);
        __syncthreads();  // compiler emits vmcnt(0) drain before s_barrier

        bf16x8 af[4], bfr[4];
#pragma unroll
        for (int i = 0; i < 4; ++i)
            af[i] = *(const bf16x8*)&As[(wm + i * 16 + fr) * 32 + fk];
#pragma unroll
        for (int j = 0; j < 4; ++j)
            bfr[j] = *(const bf16x8*)&Bs[(wn + j * 16 + fr) * 32 + fk];

#pragma unroll
        for (int i = 0; i < 4; ++i)
#pragma unroll
            for (int j = 0; j < 4; ++j)
                acc[i][j] = __builtin_amdgcn_mfma_f32_16x16x32_bf16(af[i], bfr[j], acc[i][j], 0, 0, 0);

        __syncthreads();  // all reads done before next staging overwrites LDS
    }

    // epilogue: C/D layout col=lane&15, row=(lane>>4)*4+reg  [measured m89/m91]
    const int col_base = bn + wn + (lane & 15);
    const int row_base = bm + wm + (lane >> 4) * 4;
#pragma unroll
    for (int j = 0; j < 4; ++j) {
        const int col = col_base + j * 16;
        const float bv = bias[col];
#pragma unroll
        for (int i = 0; i < 4; ++i) {
            const int row = row_base + i * 16;
            float* op = out + (size_t)row * Ndim + col;
#pragma unroll
            for (int r = 0; r < 4; ++r) op[(size_t)r * Ndim] = acc[i][j][r] + bv;
        }
    }
}

// ---- fallback (only if ws too small): naive fp32, correct but slow ----
__global__ void k_naive(const float* __restrict__ A, const float* __restrict__ W,
                        const float* __restrict__ Msk, const float* __restrict__ bias,
                        float* __restrict__ out) {
    int n = blockIdx.x * blockDim.x + threadIdx.x;  // output col
    int m = blockIdx.y;                             // output row
    if (n >= Ndim) return;
    const float* a = A + (size_t)m * Kdim;
    const float* w = W + (size_t)n * Kdim;
    const float* mk = Msk + (size_t)n * Kdim;
    float s = 0.f;
    for (int k = 0; k < Kdim; ++k) s += a[k] * w[k] * mk[k];
    out[(size_t)m * Ndim + n] = s + bias[n];
}

extern "C" void kernel_launch(void* const* d_in, const int* in_sizes, int n_in,
                              void* d_out, int out_size, void* d_ws, size_t ws_size,
                              hipStream_t stream) {
    const float* data   = (const float*)d_in[0];
    const float* weight = (const float*)d_in[1];
    const float* mask   = (const float*)d_in[2];
    const float* bias   = (const float*)d_in[3];
    float* out = (float*)d_out;

    const size_t needA = (size_t)Mdim * Kdim * 2;  // 64 MiB
    const size_t needB = (size_t)Ndim * Kdim * 2;  // 32 MiB
    if (ws_size < needA + needB) {
        dim3 g((Ndim + 255) / 256, Mdim);
        k_naive<<<g, 256, 0, stream>>>(data, weight, mask, bias, out);
        return;
    }

    unsigned short* Abf = (unsigned short*)d_ws;
    unsigned short* Bbf = Abf + (size_t)Mdim * Kdim;

    const int n4a = Mdim * Kdim / 4;  // 8,388,608
    k_cvt_data<<<n4a / 256, 256, 0, stream>>>((const float4*)data, (ushort4*)Abf, n4a);
    const int n4b = Ndim * Kdim / 4;  // 4,194,304
    k_cvt_w<<<n4b / 256, 256, 0, stream>>>((const float4*)weight, (const float4*)mask,
                                           (ushort4*)Bbf, n4b);

    dim3 grid(Ndim / 128, Mdim / 128);  // (32, 64) = 2048 blocks
    k_gemm<<<grid, 256, 0, stream>>>(Abf, Bbf, bias, out);
}

// Round 2
// 616.761 us; speedup vs baseline: 1.0074x; 1.0074x over previous
//
#include <hip/hip_runtime.h>
#include <hip/hip_bf16.h>

// out[M,N] = data[M,K] @ (mask*weight)[N,K]^T + bias[N];  M=8192, N=K=4096, fp32.
// R2: fuse both fp32->bf16 conversions into one grid-stride kernel with 16B
// loads AND 16B stores (was: two kernels, 8B stores). GEMM (m97-structure,
// 772 TF = known plateau for this shape) unchanged for clean attribution.

#define Mdim 8192
#define Ndim 4096
#define Kdim 4096

typedef __bf16 bf16x8 __attribute__((ext_vector_type(8)));
typedef float f32x4 __attribute__((ext_vector_type(4)));

// round-to-nearest-even fp32 -> bf16 bits
__device__ inline unsigned short f2bf(float f) {
    union { float f; unsigned u; } v;
    v.f = f;
    unsigned r = v.u + 0x7fffu + ((v.u >> 16) & 1u);
    return (unsigned short)(r >> 16);
}

__device__ inline unsigned pack2(float a, float b) {
    return (unsigned)f2bf(a) | ((unsigned)f2bf(b) << 16);
}

// async global->LDS, 16B per lane; lds_ptr per-lane = base + lane*16
#define GLOAD_LDS16(gp, lp)                                                     \
    __builtin_amdgcn_global_load_lds((const __attribute__((address_space(1))) void*)(gp), \
                                     (__attribute__((address_space(3))) void*)(lp), 16, 0, 0)

// ---- fused conversion: data->bf16 and (weight*mask)->bf16, 16B I/O ----
__global__ __launch_bounds__(256) void k_cvt_all(const float4* __restrict__ data,
                                                 const float4* __restrict__ weight,
                                                 const float4* __restrict__ mask,
                                                 uint4* __restrict__ Abf,
                                                 uint4* __restrict__ Bbf) {
    const int NA = Mdim * (Kdim / 8);  // 8-float chunks of data
    const int NB = Ndim * (Kdim / 8);  // 8-float chunks of weight/mask
    const int stride = gridDim.x * blockDim.x;
    for (int i = blockIdx.x * blockDim.x + threadIdx.x; i < NA + NB; i += stride) {
        if (i < NA) {
            const size_t j2 = 2 * (size_t)i;
            float4 v0 = data[j2], v1 = data[j2 + 1];
            uint4 o;
            o.x = pack2(v0.x, v0.y); o.y = pack2(v0.z, v0.w);
            o.z = pack2(v1.x, v1.y); o.w = pack2(v1.z, v1.w);
            Abf[i] = o;
        } else {
            const size_t j = (size_t)(i - NA);
            const size_t j2 = 2 * j;
            float4 w0 = weight[j2], w1 = weight[j2 + 1];
            float4 m0 = mask[j2],   m1 = mask[j2 + 1];
            uint4 o;
            o.x = pack2(w0.x * m0.x, w0.y * m0.y);
            o.y = pack2(w0.z * m0.z, w0.w * m0.w);
            o.z = pack2(w1.x * m1.x, w1.y * m1.y);
            o.w = pack2(w1.z * m1.z, w1.w * m1.w);
            Bbf[j] = o;
        }
    }
}

// ---- bf16 MFMA GEMM: C = A * B^T + bias (m97 structure, unchanged) ----
__global__ __launch_bounds__(256) void k_gemm(const unsigned short* __restrict__ A,
                                              const unsigned short* __restrict__ B,
                                              const float* __restrict__ bias,
                                              float* __restrict__ out) {
    __shared__ unsigned short As[128 * 32];  // 8 KB, row-major [128][32]
    __shared__ unsigned short Bs[128 * 32];  // 8 KB

    const int tid  = threadIdx.x;
    const int lane = tid & 63;
    const int wave = tid >> 6;
    const int wm   = (wave >> 1) * 64;
    const int wn   = (wave & 1) * 64;
    const int bm   = blockIdx.y * 128;
    const int bn   = blockIdx.x * 128;

    const int ar = lane >> 2;
    const int ac = (lane & 3) * 8;
    const unsigned short* Ag0 = A + (size_t)(bm + wave * 32 + ar) * Kdim + ac;
    const unsigned short* Ag1 = Ag0 + (size_t)16 * Kdim;
    const unsigned short* Bg0 = B + (size_t)(bn + wave * 32 + ar) * Kdim + ac;
    const unsigned short* Bg1 = Bg0 + (size_t)16 * Kdim;
    unsigned short* Al0 = As + wave * 1024 + lane * 8;
    unsigned short* Al1 = Al0 + 512;
    unsigned short* Bl0 = Bs + wave * 1024 + lane * 8;
    unsigned short* Bl1 = Bl0 + 512;

    f32x4 zero = {0.f, 0.f, 0.f, 0.f};
    f32x4 acc[4][4];
#pragma unroll
    for (int i = 0; i < 4; ++i)
#pragma unroll
        for (int j = 0; j < 4; ++j) acc[i][j] = zero;

    const int fr = lane & 15;
    const int fk = (lane >> 4) * 8;

    for (int k0 = 0; k0 < Kdim; k0 += 32) {
        GLOAD_LDS16(Ag0 + k0, Al0);
        GLOAD_LDS16(Ag1 + k0, Al1);
        GLOAD_LDS16(Bg0 + k0, Bl0);
        GLOAD_LDS16(Bg1 + k0, Bl1);
        __syncthreads();

        bf16x8 af[4], bfr[4];
#pragma unroll
        for (int i = 0; i < 4; ++i)
            af[i] = *(const bf16x8*)&As[(wm + i * 16 + fr) * 32 + fk];
#pragma unroll
        for (int j = 0; j < 4; ++j)
            bfr[j] = *(const bf16x8*)&Bs[(wn + j * 16 + fr) * 32 + fk];

#pragma unroll
        for (int i = 0; i < 4; ++i)
#pragma unroll
            for (int j = 0; j < 4; ++j)
                acc[i][j] = __builtin_amdgcn_mfma_f32_16x16x32_bf16(af[i], bfr[j], acc[i][j], 0, 0, 0);

        __syncthreads();
    }

    // epilogue: C/D layout col=lane&15, row=(lane>>4)*4+reg  [measured m89/m91]
    const int col_base = bn + wn + (lane & 15);
    const int row_base = bm + wm + (lane >> 4) * 4;
#pragma unroll
    for (int j = 0; j < 4; ++j) {
        const int col = col_base + j * 16;
        const float bv = bias[col];
#pragma unroll
        for (int i = 0; i < 4; ++i) {
            const int row = row_base + i * 16;
            float* op = out + (size_t)row * Ndim + col;
#pragma unroll
            for (int r = 0; r < 4; ++r) op[(size_t)r * Ndim] = acc[i][j][r] + bv;
        }
    }
}

// ---- fallback (only if ws too small): naive fp32, correct but slow ----
__global__ void k_naive(const float* __restrict__ A, const float* __restrict__ W,
                        const float* __restrict__ Msk, const float* __restrict__ bias,
                        float* __restrict__ out) {
    int n = blockIdx.x * blockDim.x + threadIdx.x;
    int m = blockIdx.y;
    if (n >= Ndim) return;
    const float* a = A + (size_t)m * Kdim;
    const float* w = W + (size_t)n * Kdim;
    const float* mk = Msk + (size_t)n * Kdim;
    float s = 0.f;
    for (int k = 0; k < Kdim; ++k) s += a[k] * w[k] * mk[k];
    out[(size_t)m * Ndim + n] = s + bias[n];
}

extern "C" void kernel_launch(void* const* d_in, const int* in_sizes, int n_in,
                              void* d_out, int out_size, void* d_ws, size_t ws_size,
                              hipStream_t stream) {
    const float* data   = (const float*)d_in[0];
    const float* weight = (const float*)d_in[1];
    const float* mask   = (const float*)d_in[2];
    const float* bias   = (const float*)d_in[3];
    float* out = (float*)d_out;

    const size_t needA = (size_t)Mdim * Kdim * 2;  // 64 MiB
    const size_t needB = (size_t)Ndim * Kdim * 2;  // 32 MiB
    if (ws_size < needA + needB) {
        dim3 g((Ndim + 255) / 256, Mdim);
        k_naive<<<g, 256, 0, stream>>>(data, weight, mask, bias, out);
        return;
    }

    unsigned short* Abf = (unsigned short*)d_ws;
    unsigned short* Bbf = Abf + (size_t)Mdim * Kdim;

    // one fused conversion kernel: 4096 blocks x 256, grid-stride (~6 iters)
    k_cvt_all<<<4096, 256, 0, stream>>>((const float4*)data, (const float4*)weight,
                                        (const float4*)mask, (uint4*)Abf, (uint4*)Bbf);

    dim3 grid(Ndim / 128, Mdim / 128);  // (32, 64) = 2048 blocks
    k_gemm<<<grid, 256, 0, stream>>>(Abf, Bbf, bias, out);
}